// Round 8
// baseline (8049.964 us; speedup 1.0000x reference)
//
#include <hip/hip_runtime.h>
#include <math.h>

#define HDIM 1024
#define BDIM 64
#define TDIM 512
#define KIN  128
#define NBLK 128
#define NTHR 512            // 8 waves
#define FRAME (HDIM * BDIM) // halfs per ring frame
#define NGRP 8
#define GSZ  (NBLK / NGRP)  // 16

typedef _Float16 f16;
typedef __attribute__((ext_vector_type(2))) _Float16 f16x2;
typedef __attribute__((ext_vector_type(8))) _Float16 f16x8;
typedef __attribute__((ext_vector_type(4))) float f32x4;

#define MFMA16(a, b, c) __builtin_amdgcn_mfma_f32_16x16x32_f16((a), (b), (c), 0, 0, 0)

__device__ __forceinline__ float sigm(float x) { return 1.0f / (1.0f + expf(-x)); }

// ---------------------------------------------------------------------------
// Coherence-point (L3) ring I/O — bypasses L1/L2; no cache-wide fences needed.
// ---------------------------------------------------------------------------
__device__ __forceinline__ f16x8 ld_cg(const f16* p) {
    f16x8 r;
    asm volatile("global_load_dwordx4 %0, %1, off sc0 sc1"
                 : "=v"(r) : "v"(p) : "memory");
    return r;
}
#define VM_WAIT8(r0, r1, r2, r3, r4, r5, r6, r7)                         \
    asm volatile("s_waitcnt vmcnt(0)"                                    \
                 : "+v"(r0), "+v"(r1), "+v"(r2), "+v"(r3),               \
                   "+v"(r4), "+v"(r5), "+v"(r6), "+v"(r7))
#define VM_WAIT16(a0,a1,a2,a3,a4,a5,a6,a7,b0,b1,b2,b3,b4,b5,b6,b7)       \
    asm volatile("s_waitcnt vmcnt(0)"                                    \
                 : "+v"(a0), "+v"(a1), "+v"(a2), "+v"(a3),               \
                   "+v"(a4), "+v"(a5), "+v"(a6), "+v"(a7),               \
                   "+v"(b0), "+v"(b1), "+v"(b2), "+v"(b3),               \
                   "+v"(b4), "+v"(b5), "+v"(b6), "+v"(b7))

__device__ __forceinline__ void st_cg(f16* p, f16 v) {
    unsigned short u = __builtin_bit_cast(unsigned short, v);
    asm volatile("global_store_short %0, %1, off sc0 sc1"
                 :: "v"(p), "v"(u) : "memory");
}
#define VM_DRAIN() asm volatile("s_waitcnt vmcnt(0)" ::: "memory")

// ---------------------------------------------------------------------------
// Fence-free hierarchical grid barrier (arrive+wait fused), 128 arrivals:
//   [grp*32] group counters (8 lines) | [256] root cnt | [288] root flag |
//   [320+grp*32] group broadcast flags.
// Caller guarantees per-wave vmcnt(0) drain of its sc0sc1 stores beforehand.
// ---------------------------------------------------------------------------
__device__ __forceinline__ void grid_bar(unsigned* base, int grp, unsigned ep) {
    __syncthreads();
    if (threadIdx.x == 0) {
        unsigned o = __hip_atomic_fetch_add(base + grp * 32, 1u,
                                            __ATOMIC_RELAXED,
                                            __HIP_MEMORY_SCOPE_AGENT);
        if (o == ep * GSZ - 1u) {                       // group leader
            unsigned r = __hip_atomic_fetch_add(base + 256, 1u,
                                                __ATOMIC_RELAXED,
                                                __HIP_MEMORY_SCOPE_AGENT);
            if (r == ep * NGRP - 1u)
                __hip_atomic_store(base + 288, ep, __ATOMIC_RELAXED,
                                   __HIP_MEMORY_SCOPE_AGENT);
            while (__hip_atomic_load(base + 288, __ATOMIC_RELAXED,
                                     __HIP_MEMORY_SCOPE_AGENT) < ep)
                __builtin_amdgcn_s_sleep(1);
            __hip_atomic_store(base + 320 + grp * 32, ep, __ATOMIC_RELAXED,
                               __HIP_MEMORY_SCOPE_AGENT);
        } else {
            while (__hip_atomic_load(base + 320 + grp * 32, __ATOMIC_RELAXED,
                                     __HIP_MEMORY_SCOPE_AGENT) < ep)
                __builtin_amdgcn_s_sleep(1);
        }
    }
    __syncthreads();
}

// ---------------------------------------------------------------------------
__global__ void cvt_w(const float* __restrict__ src, f16* __restrict__ dst, int n2) {
    int i = blockIdx.x * blockDim.x + threadIdx.x;
    if (i < n2) {
        float2 a = ((const float2*)src)[i];
        f16x2 o = {(f16)a.x, (f16)a.y};
        ((f16x2*)dst)[i] = o;
    }
}

// x[b][t][k] fp32 -> xP[t][b][k] fp16
__global__ void cvt_x(const float* __restrict__ x, f16* __restrict__ xP) {
    int P = blockIdx.x * blockDim.x + threadIdx.x;    // pair index
    if (P >= TDIM * BDIM * (KIN / 2)) return;
    int kp = P & 63;
    int b  = (P >> 6) & 63;
    int t  = P >> 12;
    float2 v = ((const float2*)x)[((size_t)b * TDIM + t) * (KIN / 2) + kp];
    f16x2 o = {(f16)v.x, (f16)v.y};
    ((f16x2*)xP)[((size_t)t * BDIM + b) * (KIN / 2) + kp] = o;
}

// ---------------------------------------------------------------------------
// Fused 2-layer LSTM, MFMA, weights stationary in VGPRs.
// 128 blocks x 8 waves. Block owns 8 hidden cols (2 MFMA n-tiles of 16 gate
// rows). Wave w = K-slice [w*128, w*128+128). Every wave is an owner wave:
// col il=w, lane=batch. Reduction: waves 0..3 write partials, 4..7 fold-add,
// owners sum 4. Ring I/O via sc0sc1 (L3-coherent, fence-free barrier).
// ---------------------------------------------------------------------------
__global__ void __launch_bounds__(NTHR, 2) lstm_fused(
    const f16* __restrict__ xP,
    const f16* __restrict__ Wc0, const f16* __restrict__ Wh0,
    const float* __restrict__ bih0, const float* __restrict__ bhh0,
    const f16* __restrict__ Wc1, const f16* __restrict__ Wh1,
    const float* __restrict__ bih1, const float* __restrict__ bhh1,
    f16* ring1, f16* ring2, unsigned* bar) {

    // slot((nt*4+p2)*4+mt)*324 + n*20 + quad*4  — 32 slots, ~41.6 KB
    __shared__ float red[32 * 324 + 16];

    const int tid  = threadIdx.x;
    const int lane = tid & 63;
    const int w    = __builtin_amdgcn_readfirstlane(tid >> 6);   // 0..7
    const int iu8  = __builtin_amdgcn_readfirstlane((int)blockIdx.x * 8);
    const int grp  = __builtin_amdgcn_readfirstlane((int)blockIdx.x >> 4);

    const int n    = lane & 15;
    const int quad = lane >> 4;
    const int am   = lane & 15;

    // ---- preload stationary weight fragments ----
    f16x8 B1h[2][4], B2i[2][4], B2h[2][4];   // [ntile][j]
    f16x8 B1x[2];                            // valid for w<4
    #pragma unroll
    for (int nt = 0; nt < 2; ++nt) {
        const int wr = iu8 + nt * 4 + (n >> 2) + (n & 3) * HDIM;
        #pragma unroll
        for (int j = 0; j < 4; ++j) {
            const int ks = w * 128 + j * 32 + quad * 8;
            B1h[nt][j] = *(const f16x8*)(Wh0 + (size_t)wr * HDIM + ks);
            B2i[nt][j] = *(const f16x8*)(Wc1 + (size_t)wr * HDIM + ks);
            B2h[nt][j] = *(const f16x8*)(Wh1 + (size_t)wr * HDIM + ks);
        }
        if (w < 4)
            B1x[nt] = *(const f16x8*)(Wc0 + (size_t)wr * KIN + w * 32 + quad * 8);
    }

    // ---- owner state: col icol = iu8 + w, batch = lane ----
    const int il = w;
    const int m  = lane;
    const int icol = iu8 + il;
    float bias1[4], bias2[4];
    float c1 = 0.f, c2 = 0.f;
    #pragma unroll
    for (int g = 0; g < 4; ++g) {
        bias1[g] = bih0[icol + g * HDIM] + bhh0[icol + g * HDIM];
        bias2[g] = bih1[icol + g * HDIM] + bhh1[icol + g * HDIM];
    }
    st_cg(ring1 + FRAME + (size_t)m * HDIM + icol, (f16)0.f);   // h^{(-1)}=0
    st_cg(ring2 + FRAME + (size_t)m * HDIM + icol, (f16)0.f);
    VM_DRAIN();

    unsigned ep = 1;
    grid_bar(bar, grp, ep++);

    for (int s = 0; s <= TDIM; ++s) {
        const f16* r1p = ring1 + (size_t)((s + 1) & 1) * FRAME;  // h1^{(s-1)}
        const f16* r2p = ring2 + (size_t)(s & 1) * FRAME;        // h2^{(s-2)}

        f32x4 acc[2][4], acc2[2][4];
        #pragma unroll
        for (int nt = 0; nt < 2; ++nt)
            #pragma unroll
            for (int mt = 0; mt < 4; ++mt) {
                acc[nt][mt]  = (f32x4){0.f, 0.f, 0.f, 0.f};
                acc2[nt][mt] = (f32x4){0.f, 0.f, 0.f, 0.f};
            }

        // ---- A1 = h1^{(s-1)} fragments, streamed in 2 halves of 8 ----
        f16x8 Aa[2][4], Ab[2][4];
        #pragma unroll
        for (int jj = 0; jj < 2; ++jj) {
            const int ks = w * 128 + jj * 32 + quad * 8;
            #pragma unroll
            for (int mt = 0; mt < 4; ++mt)
                Aa[jj][mt] = ld_cg(r1p + (size_t)(mt * 16 + am) * HDIM + ks);
        }
        VM_WAIT8(Aa[0][0], Aa[0][1], Aa[0][2], Aa[0][3],
                 Aa[1][0], Aa[1][1], Aa[1][2], Aa[1][3]);
        #pragma unroll
        for (int jj = 0; jj < 2; ++jj) {
            const int ks = w * 128 + (2 + jj) * 32 + quad * 8;
            #pragma unroll
            for (int mt = 0; mt < 4; ++mt)
                Ab[jj][mt] = ld_cg(r1p + (size_t)(mt * 16 + am) * HDIM + ks);
        }
        // MFMA half a: feeds both layer1 (B1h) and layer2-Wih1 (B2i)
        #pragma unroll
        for (int jj = 0; jj < 2; ++jj)
            #pragma unroll
            for (int nt = 0; nt < 2; ++nt)
                #pragma unroll
                for (int mt = 0; mt < 4; ++mt) {
                    acc[nt][mt]  = MFMA16(Aa[jj][mt], B1h[nt][jj], acc[nt][mt]);
                    acc2[nt][mt] = MFMA16(Aa[jj][mt], B2i[nt][jj], acc2[nt][mt]);
                }
        VM_WAIT8(Ab[0][0], Ab[0][1], Ab[0][2], Ab[0][3],
                 Ab[1][0], Ab[1][1], Ab[1][2], Ab[1][3]);
        #pragma unroll
        for (int jj = 0; jj < 2; ++jj)
            #pragma unroll
            for (int nt = 0; nt < 2; ++nt)
                #pragma unroll
                for (int mt = 0; mt < 4; ++mt) {
                    acc[nt][mt]  = MFMA16(Ab[jj][mt], B1h[nt][2 + jj], acc[nt][mt]);
                    acc2[nt][mt] = MFMA16(Ab[jj][mt], B2i[nt][2 + jj], acc2[nt][mt]);
                }

        // ---- x-part (waves 0..3, normal cached loads) ----
        if (w < 4) {
            const int ts = (s < TDIM) ? s : (TDIM - 1);
            const f16* xb = xP + (size_t)ts * BDIM * KIN;
            const int kx = w * 32 + quad * 8;
            #pragma unroll
            for (int mt = 0; mt < 4; ++mt) {
                f16x8 ax = *(const f16x8*)(xb + (size_t)(mt * 16 + am) * KIN + kx);
                #pragma unroll
                for (int nt = 0; nt < 2; ++nt)
                    acc[nt][mt] = MFMA16(ax, B1x[nt], acc[nt][mt]);
            }
        }

        // ---- prefetch A2 = h2^{(s-2)} fragments (16 loads in flight) ----
        f16x8 A2a[2][4], A2b[2][4];
        #pragma unroll
        for (int jj = 0; jj < 2; ++jj) {
            const int ks = w * 128 + jj * 32 + quad * 8;
            #pragma unroll
            for (int mt = 0; mt < 4; ++mt)
                A2a[jj][mt] = ld_cg(r2p + (size_t)(mt * 16 + am) * HDIM + ks);
        }
        #pragma unroll
        for (int jj = 0; jj < 2; ++jj) {
            const int ks = w * 128 + (2 + jj) * 32 + quad * 8;
            #pragma unroll
            for (int mt = 0; mt < 4; ++mt)
                A2b[jj][mt] = ld_cg(r2p + (size_t)(mt * 16 + am) * HDIM + ks);
        }

        // ---- phase-1 reduction: waves 0..3 write, 4..7 fold-add ----
        const int p2 = w & 3;
        if (w < 4) {
            #pragma unroll
            for (int nt = 0; nt < 2; ++nt)
                #pragma unroll
                for (int mt = 0; mt < 4; ++mt)
                    *(f32x4*)&red[(((nt * 4 + p2) * 4) + mt) * 324 + n * 20 + quad * 4] =
                        acc[nt][mt];
        }
        __syncthreads();
        if (w >= 4) {
            #pragma unroll
            for (int nt = 0; nt < 2; ++nt)
                #pragma unroll
                for (int mt = 0; mt < 4; ++mt) {
                    float* a = &red[(((nt * 4 + p2) * 4) + mt) * 324 + n * 20 + quad * 4];
                    f32x4 v = *(f32x4*)a;
                    *(f32x4*)a = v + acc[nt][mt];
                }
        }
        __syncthreads();

        // ---- reduce1: every wave owns col il=w; gates -> h1 store ----
        if (s < TDIM) {
            const int ntl = il >> 2, cl = il & 3;
            const int mtm = m >> 4, qm = m & 15;
            float g4[4];
            #pragma unroll
            for (int g = 0; g < 4; ++g) {
                float sum = bias1[g];
                #pragma unroll
                for (int pp = 0; pp < 4; ++pp)
                    sum += red[(((ntl * 4 + pp) * 4) + mtm) * 324 + (cl * 4 + g) * 20 + qm];
                g4[g] = sum;
            }
            float ig = sigm(g4[0]), fg = sigm(g4[1]);
            float gg = tanhf(g4[2]), og = sigm(g4[3]);
            c1 = fg * c1 + ig * gg;
            float h = og * tanhf(c1);
            st_cg(ring1 + (size_t)(s & 1) * FRAME + (size_t)m * HDIM + icol, (f16)h);
        }

        // ---- phase 2: wait A2, MFMA Whh1 part ----
        VM_WAIT16(A2a[0][0], A2a[0][1], A2a[0][2], A2a[0][3],
                  A2a[1][0], A2a[1][1], A2a[1][2], A2a[1][3],
                  A2b[0][0], A2b[0][1], A2b[0][2], A2b[0][3],
                  A2b[1][0], A2b[1][1], A2b[1][2], A2b[1][3]);
        #pragma unroll
        for (int jj = 0; jj < 2; ++jj)
            #pragma unroll
            for (int nt = 0; nt < 2; ++nt)
                #pragma unroll
                for (int mt = 0; mt < 4; ++mt) {
                    acc2[nt][mt] = MFMA16(A2a[jj][mt], B2h[nt][jj], acc2[nt][mt]);
                    acc2[nt][mt] = MFMA16(A2b[jj][mt], B2h[nt][2 + jj], acc2[nt][mt]);
                }

        __syncthreads();   // reduce1 readers done; red reusable

        // ---- phase-2 reduction ----
        if (w < 4) {
            #pragma unroll
            for (int nt = 0; nt < 2; ++nt)
                #pragma unroll
                for (int mt = 0; mt < 4; ++mt)
                    *(f32x4*)&red[(((nt * 4 + p2) * 4) + mt) * 324 + n * 20 + quad * 4] =
                        acc2[nt][mt];
        }
        __syncthreads();
        if (w >= 4) {
            #pragma unroll
            for (int nt = 0; nt < 2; ++nt)
                #pragma unroll
                for (int mt = 0; mt < 4; ++mt) {
                    float* a = &red[(((nt * 4 + p2) * 4) + mt) * 324 + n * 20 + quad * 4];
                    f32x4 v = *(f32x4*)a;
                    *(f32x4*)a = v + acc2[nt][mt];
                }
        }
        __syncthreads();

        // ---- reduce2: layer2 gates -> h2 store ----
        if (s >= 1) {
            const int ntl = il >> 2, cl = il & 3;
            const int mtm = m >> 4, qm = m & 15;
            float g4[4];
            #pragma unroll
            for (int g = 0; g < 4; ++g) {
                float sum = bias2[g];
                #pragma unroll
                for (int pp = 0; pp < 4; ++pp)
                    sum += red[(((ntl * 4 + pp) * 4) + mtm) * 324 + (cl * 4 + g) * 20 + qm];
                g4[g] = sum;
            }
            float ig = sigm(g4[0]), fg = sigm(g4[1]);
            float gg = tanhf(g4[2]), og = sigm(g4[3]);
            c2 = fg * c2 + ig * gg;
            float h = og * tanhf(c2);
            st_cg(ring2 + (size_t)((s + 1) & 1) * FRAME + (size_t)m * HDIM + icol, (f16)h);
        }
        VM_DRAIN();   // h1+h2 stores visible at L3 before arrival

        grid_bar(bar, grp, ep++);
    }
    // final h2^{(511)} is in ring2 frame 1
}

// ---------------------------------------------------------------------------
// out[b] = dot(h2[b, :], fc_w) + fc_b.   h2 is [batch][H] fp16.
// ---------------------------------------------------------------------------
__global__ void fc_kernel(const f16* __restrict__ h2f,
                          const float* __restrict__ fcw,
                          const float* __restrict__ fcb,
                          float* __restrict__ out) {
    __shared__ float red[256];
    const int tid = threadIdx.x;
    const int b = tid >> 2, q = tid & 3;
    float s = 0.f;
    for (int i = q * (HDIM / 4); i < (q + 1) * (HDIM / 4); ++i)
        s = fmaf((float)h2f[(size_t)b * HDIM + i], fcw[i], s);
    red[tid] = s;
    __syncthreads();
    if (q == 0)
        out[b] = red[tid] + red[tid + 1] + red[tid + 2] + red[tid + 3] + fcb[0];
}

// ---------------------------------------------------------------------------
extern "C" void kernel_launch(void* const* d_in, const int* in_sizes, int n_in,
                              void* d_out, int out_size, void* d_ws, size_t ws_size,
                              hipStream_t stream) {
    const float* x    = (const float*)d_in[0];
    const float* Wih0 = (const float*)d_in[1];
    const float* Whh0 = (const float*)d_in[2];
    const float* bih0 = (const float*)d_in[3];
    const float* bhh0 = (const float*)d_in[4];
    const float* Wih1 = (const float*)d_in[5];
    const float* Whh1 = (const float*)d_in[6];
    const float* bih1 = (const float*)d_in[7];
    const float* bhh1 = (const float*)d_in[8];
    const float* fcw  = (const float*)d_in[9];
    const float* fcb  = (const float*)d_in[10];
    float* out = (float*)d_out;

    // workspace (halfs): xP | Wc0 | Wh0 | Wc1 | Wh1 | ring1 | ring2 | bar
    f16* xPd   = (f16*)d_ws;
    f16* Wc0   = xPd + (size_t)TDIM * BDIM * KIN;
    f16* Wh0   = Wc0 + (size_t)4 * HDIM * KIN;
    f16* Wc1   = Wh0 + (size_t)4 * HDIM * HDIM;
    f16* Wh1   = Wc1 + (size_t)4 * HDIM * HDIM;
    f16* ring1 = Wh1 + (size_t)4 * HDIM * HDIM;
    f16* ring2 = ring1 + 2 * FRAME;
    unsigned* bar = (unsigned*)(ring2 + 2 * FRAME);

    hipMemsetAsync(bar, 0, 4096, stream);
    {
        int n2 = 4 * HDIM * KIN / 2;
        cvt_w<<<dim3((n2 + 255) / 256), dim3(256), 0, stream>>>(Wih0, Wc0, n2);
        n2 = 4 * HDIM * HDIM / 2;
        cvt_w<<<dim3((n2 + 255) / 256), dim3(256), 0, stream>>>(Whh0, Wh0, n2);
        cvt_w<<<dim3((n2 + 255) / 256), dim3(256), 0, stream>>>(Whh1, Wh1, n2);
        cvt_w<<<dim3((n2 + 255) / 256), dim3(256), 0, stream>>>(Wih1, Wc1, n2);
    }
    {
        int np = TDIM * BDIM * (KIN / 2);
        cvt_x<<<dim3((np + 255) / 256), dim3(256), 0, stream>>>(x, xPd);
    }

    void* args[12];
    args[0]  = (void*)&xPd;
    args[1]  = (void*)&Wc0;
    args[2]  = (void*)&Wh0;
    args[3]  = (void*)&bih0;
    args[4]  = (void*)&bhh0;
    args[5]  = (void*)&Wc1;
    args[6]  = (void*)&Wh1;
    args[7]  = (void*)&bih1;
    args[8]  = (void*)&bhh1;
    args[9]  = (void*)&ring1;
    args[10] = (void*)&ring2;
    args[11] = (void*)&bar;
    hipLaunchCooperativeKernel(reinterpret_cast<void*>(lstm_fused), dim3(NBLK), dim3(NTHR),
                               args, 0, stream);

    fc_kernel<<<dim3(1), dim3(256), 0, stream>>>(ring2 + FRAME, fcw, fcb, out);
}

// Round 9
// 3225.454 us; speedup vs baseline: 2.4958x; 2.4958x over previous
//
#include <hip/hip_runtime.h>
#include <math.h>

#define HDIM 1024
#define BDIM 64
#define TDIM 512
#define KIN  128
#define NBLK 256
#define NTHR 1024           // 16 waves
#define FRAME (HDIM * BDIM) // halfs per ring frame

typedef _Float16 f16;
typedef __attribute__((ext_vector_type(2))) _Float16 f16x2;
typedef __attribute__((ext_vector_type(8))) _Float16 f16x8;
typedef __attribute__((ext_vector_type(4))) float f32x4;

#define MFMA16(a, b, c) __builtin_amdgcn_mfma_f32_16x16x32_f16((a), (b), (c), 0, 0, 0)

__device__ __forceinline__ float sigm(float x) { return 1.0f / (1.0f + expf(-x)); }

// ---------------------------------------------------------------------------
// Ring layout (halfs): idx(k, m) = (k>>3)*512 + m*8 + (k&7).
//  - A-fragment load (8 consecutive k, aligned): one dwordx4 per lane.
//  - h-store: block's 4 cols x 64 batches = 64 lanes x dwordx2, contiguous.
// All ring I/O is sc0sc1 (coherent at L3, no cache-wide fences needed).
// ---------------------------------------------------------------------------
__device__ __forceinline__ f16x8 ld_cg(const f16* p) {
    f16x8 r;
    asm volatile("global_load_dwordx4 %0, %1, off sc0 sc1"
                 : "=v"(r) : "v"(p) : "memory");
    return r;
}
#define VM_WAIT8(r0, r1, r2, r3, r4, r5, r6, r7)                         \
    asm volatile("s_waitcnt vmcnt(0)"                                    \
                 : "+v"(r0), "+v"(r1), "+v"(r2), "+v"(r3),               \
                   "+v"(r4), "+v"(r5), "+v"(r6), "+v"(r7))

__device__ __forceinline__ void st_cg8(f16* p, uint2 v) {
    asm volatile("global_store_dwordx2 %0, %1, off sc0 sc1"
                 :: "v"(p), "v"(v) : "memory");
}
#define VM_DRAIN() asm volatile("s_waitcnt vmcnt(0)" ::: "memory")

// ---------------------------------------------------------------------------
// Flat-8 fence-free barrier: monotonic arrival counters on 8 parallel 128B
// lines (32 blocks each); wait = poll sum >= target. 2-hop chain (add, poll)
// vs the r6 tree's 4 hops. Run-ahead bounded at 1 arrival/block -> sum
// inflation < NBLK, cannot fake an epoch.
// ---------------------------------------------------------------------------
__device__ __forceinline__ void bar_add(unsigned* base, int slot) {
    __hip_atomic_fetch_add(base + slot * 32, 1u, __ATOMIC_RELAXED,
                           __HIP_MEMORY_SCOPE_AGENT);
}
__device__ __forceinline__ void bar_wait(unsigned* base, unsigned target) {
    for (;;) {
        unsigned sum = 0;
        #pragma unroll
        for (int i = 0; i < 8; ++i)
            sum += __hip_atomic_load(base + i * 32, __ATOMIC_RELAXED,
                                     __HIP_MEMORY_SCOPE_AGENT);
        if (sum >= target) break;
        __builtin_amdgcn_s_sleep(1);
    }
}

// ---------------------------------------------------------------------------
__global__ void cvt_w(const float* __restrict__ src, f16* __restrict__ dst, int n2) {
    int i = blockIdx.x * blockDim.x + threadIdx.x;
    if (i < n2) {
        float2 a = ((const float2*)src)[i];
        f16x2 o = {(f16)a.x, (f16)a.y};
        ((f16x2*)dst)[i] = o;
    }
}

// x[b][t][k] fp32 -> xP[t][b][k] fp16
__global__ void cvt_x(const float* __restrict__ x, f16* __restrict__ xP) {
    int P = blockIdx.x * blockDim.x + threadIdx.x;    // pair index
    if (P >= TDIM * BDIM * (KIN / 2)) return;
    int kp = P & 63;
    int b  = (P >> 6) & 63;
    int t  = P >> 12;
    float2 v = ((const float2*)x)[((size_t)b * TDIM + t) * (KIN / 2) + kp];
    f16x2 o = {(f16)v.x, (f16)v.y};
    ((f16x2*)xP)[((size_t)t * BDIM + b) * (KIN / 2) + kp] = o;
}

// ---------------------------------------------------------------------------
// Fused 2-layer LSTM, MFMA, weights stationary in VGPRs (r7 compute shape:
// 256 blocks x 16 waves, 4 cols/block, wave K-slice 64).
// New: octet ring layout; LDS-staged coalesced h-stores by dedicated waves
// (w8 -> h1+arriveA mid-iter, w9 -> h2+arriveB at end); split flat barriers
// with arrive-early / wait-late overlap.
// ---------------------------------------------------------------------------
__global__ void __launch_bounds__(NTHR, 4) lstm_fused(
    const f16* __restrict__ xP,
    const f16* __restrict__ Wc0, const f16* __restrict__ Wh0,
    const float* __restrict__ bih0, const float* __restrict__ bhh0,
    const f16* __restrict__ Wc1, const f16* __restrict__ Wh1,
    const float* __restrict__ bih1, const float* __restrict__ bhh1,
    f16* ring1, f16* ring2, unsigned* barA, unsigned* barB) {

    __shared__ float red[32 * 324 + 16];          // ~41.6 KB padded slots
    __shared__ __align__(16) f16 hbuf1[BDIM * 4]; // owner h1 staging
    __shared__ __align__(16) f16 hbuf2[BDIM * 4];

    const int tid  = threadIdx.x;
    const int lane = tid & 63;
    const int w    = __builtin_amdgcn_readfirstlane(tid >> 6);   // 0..15
    const int bid  = (int)blockIdx.x;
    const int iu4  = __builtin_amdgcn_readfirstlane(bid * 4);
    const int slot = bid & 7;

    const int n    = lane & 15;
    const int quad = lane >> 4;
    const int am   = lane & 15;
    const int wrow = iu4 + (n >> 2) + (n & 3) * HDIM;

    // block's h region in octet layout
    const int oct4 = iu4 >> 3;        // octet index of block's 4 cols
    const int coff = iu4 & 7;         // 0 or 4 within octet

    // ---- preload stationary weight fragments ----
    f16x8 B1x;
    f16x8 B1h[2], B2i[2], B2h[2];
    {
        const int kq = quad * 8;
        if (w < 4)
            B1x = *(const f16x8*)(Wc0 + (size_t)wrow * KIN + w * 32 + kq);
        #pragma unroll
        for (int j = 0; j < 2; ++j) {
            const int ks = (2 * w + j) * 32 + kq;
            B1h[j] = *(const f16x8*)(Wh0 + (size_t)wrow * HDIM + ks);
            B2i[j] = *(const f16x8*)(Wc1 + (size_t)wrow * HDIM + ks);
            B2h[j] = *(const f16x8*)(Wh1 + (size_t)wrow * HDIM + ks);
        }
    }

    // ---- owner state (waves 0..3: col icol = iu4 + w, batch = lane) ----
    float bias1[4], bias2[4];
    float c1 = 0.f, c2 = 0.f;
    const int il = w;
    const int m  = lane;
    if (w < 4) {
        const int i = iu4 + il;
        #pragma unroll
        for (int g = 0; g < 4; ++g) {
            bias1[g] = bih0[i + g * HDIM] + bhh0[i + g * HDIM];
            bias2[g] = bih1[i + g * HDIM] + bhh1[i + g * HDIM];
        }
    }

    // ---- init: zero h^{(-1)} (frame 1) via coalesced stores + arrive ----
    if (w == 8) {
        uint2 z = {0u, 0u};
        st_cg8(ring1 + FRAME + oct4 * 512 + lane * 8 + coff, z);
        VM_DRAIN();
        if (lane == 0) bar_add(barA, slot);
    }
    if (w == 9) {
        uint2 z = {0u, 0u};
        st_cg8(ring2 + FRAME + oct4 * 512 + lane * 8 + coff, z);
        VM_DRAIN();
        if (lane == 0) bar_add(barB, slot);
    }

    for (int s = 0; s <= TDIM; ++s) {
        const f16* r1p = ring1 + (size_t)((s + 1) & 1) * FRAME;  // h1^{(s-1)}
        const f16* r2p = ring2 + (size_t)(s & 1) * FRAME;        // h2^{(s-2)}

        // ---- wait for h1^{(s-1)} (target: initial + iters 0..s-1) ----
        if (tid == 0) bar_wait(barA, (unsigned)(s + 1) * NBLK);
        __syncthreads();   // S1 (also protects red/hbuf reuse from prev iter)

        // ---- A1 fragments (octet layout: one dwordx4 each) ----
        f16x8 A1[2][4];
        #pragma unroll
        for (int j = 0; j < 2; ++j) {
            const int oct = (2 * w + j) * 4 + quad;
            #pragma unroll
            for (int mt = 0; mt < 4; ++mt)
                A1[j][mt] = ld_cg(r1p + oct * 512 + (mt * 16 + am) * 8);
        }
        VM_WAIT8(A1[0][0], A1[0][1], A1[0][2], A1[0][3],
                 A1[1][0], A1[1][1], A1[1][2], A1[1][3]);

        // ---- phase 1 (layer1) + layer2-Wih1 part (both consume A1) ----
        f32x4 acc[4], acc2[4];
        #pragma unroll
        for (int mt = 0; mt < 4; ++mt) {
            acc[mt]  = (f32x4){0.f, 0.f, 0.f, 0.f};
            acc2[mt] = (f32x4){0.f, 0.f, 0.f, 0.f};
        }
        #pragma unroll
        for (int j = 0; j < 2; ++j)
            #pragma unroll
            for (int mt = 0; mt < 4; ++mt) {
                acc[mt]  = MFMA16(A1[j][mt], B1h[j], acc[mt]);
                acc2[mt] = MFMA16(A1[j][mt], B2i[j], acc2[mt]);
            }
        if (w < 4) {
            const int ts = (s < TDIM) ? s : (TDIM - 1);
            const f16* xb = xP + (size_t)ts * BDIM * KIN;
            const int kx = w * 32 + quad * 8;
            #pragma unroll
            for (int mt = 0; mt < 4; ++mt) {
                f16x8 ax = *(const f16x8*)(xb + (size_t)(mt * 16 + am) * KIN + kx);
                acc[mt] = MFMA16(ax, B1x, acc[mt]);
            }
        }

        // ---- phase-1 reduction (8 partials) ----
        const int p = w & 7;
        if (w < 8) {
            #pragma unroll
            for (int mt = 0; mt < 4; ++mt)
                *(f32x4*)&red[(p * 4 + mt) * 324 + n * 20 + quad * 4] = acc[mt];
        }
        __syncthreads();   // S2
        if (w >= 8) {
            #pragma unroll
            for (int mt = 0; mt < 4; ++mt) {
                float* a = &red[(p * 4 + mt) * 324 + n * 20 + quad * 4];
                f32x4 v = *(f32x4*)a;
                *(f32x4*)a = v + acc[mt];
            }
        }
        __syncthreads();   // S3

        // ---- reduce1: owners -> h1 into LDS; wait_B overlaps ----
        if (w < 4 && s < TDIM) {
            const int mt = m >> 4, qm = m & 15;
            float g4[4];
            #pragma unroll
            for (int g = 0; g < 4; ++g) {
                float sum = bias1[g];
                #pragma unroll
                for (int pp = 0; pp < 8; ++pp)
                    sum += red[(pp * 4 + mt) * 324 + (il * 4 + g) * 20 + qm];
                g4[g] = sum;
            }
            float ig = sigm(g4[0]), fg = sigm(g4[1]);
            float gg = tanhf(g4[2]), og = sigm(g4[3]);
            c1 = fg * c1 + ig * gg;
            hbuf1[m * 4 + il] = (f16)(og * tanhf(c1));
        }
        // wait for h2^{(s-2)} (published end of iter s-1 -> usually free)
        if (tid == 64) bar_wait(barB, (unsigned)s * NBLK);
        __syncthreads();   // S4: hbuf1 ready, wait_B done, red free

        // ---- wave 8: coalesced h1 store + arrive_A (mid-iteration) ----
        if (w == 8 && s < TDIM) {
            uint2 v = *(const uint2*)&hbuf1[lane * 4];
            st_cg8(ring1 + (size_t)(s & 1) * FRAME + oct4 * 512 + lane * 8 + coff, v);
            VM_DRAIN();
            if (lane == 0) bar_add(barA, slot);
        }

        // ---- A2 fragments of h2^{(s-2)} ----
        f16x8 A2[2][4];
        #pragma unroll
        for (int j = 0; j < 2; ++j) {
            const int oct = (2 * w + j) * 4 + quad;
            #pragma unroll
            for (int mt = 0; mt < 4; ++mt)
                A2[j][mt] = ld_cg(r2p + oct * 512 + (mt * 16 + am) * 8);
        }
        VM_WAIT8(A2[0][0], A2[0][1], A2[0][2], A2[0][3],
                 A2[1][0], A2[1][1], A2[1][2], A2[1][3]);
        #pragma unroll
        for (int j = 0; j < 2; ++j)
            #pragma unroll
            for (int mt = 0; mt < 4; ++mt)
                acc2[mt] = MFMA16(A2[j][mt], B2h[j], acc2[mt]);

        // ---- phase-2 reduction ----
        if (w < 8) {
            #pragma unroll
            for (int mt = 0; mt < 4; ++mt)
                *(f32x4*)&red[(p * 4 + mt) * 324 + n * 20 + quad * 4] = acc2[mt];
        }
        __syncthreads();   // S5
        if (w >= 8) {
            #pragma unroll
            for (int mt = 0; mt < 4; ++mt) {
                float* a = &red[(p * 4 + mt) * 324 + n * 20 + quad * 4];
                f32x4 v = *(f32x4*)a;
                *(f32x4*)a = v + acc2[mt];
            }
        }
        __syncthreads();   // S6

        // ---- reduce2: owners -> h2 into LDS ----
        if (w < 4 && s >= 1) {
            const int mt = m >> 4, qm = m & 15;
            float g4[4];
            #pragma unroll
            for (int g = 0; g < 4; ++g) {
                float sum = bias2[g];
                #pragma unroll
                for (int pp = 0; pp < 8; ++pp)
                    sum += red[(pp * 4 + mt) * 324 + (il * 4 + g) * 20 + qm];
                g4[g] = sum;
            }
            float ig = sigm(g4[0]), fg = sigm(g4[1]);
            float gg = tanhf(g4[2]), og = sigm(g4[3]);
            c2 = fg * c2 + ig * gg;
            hbuf2[m * 4 + il] = (f16)(og * tanhf(c2));
        }
        __syncthreads();   // S7: hbuf2 ready

        // ---- wave 9: coalesced h2 store + arrive_B ----
        if (w == 9 && s >= 1) {
            uint2 v = *(const uint2*)&hbuf2[lane * 4];
            st_cg8(ring2 + (size_t)((s + 1) & 1) * FRAME + oct4 * 512 + lane * 8 + coff, v);
            VM_DRAIN();
            if (lane == 0) bar_add(barB, slot);
        }
    }
    // final h2^{(511)} is in ring2 frame 1
}

// ---------------------------------------------------------------------------
// out[b] = dot(h2[b, :], fc_w) + fc_b.  h2 in octet layout.
// ---------------------------------------------------------------------------
__global__ void fc_kernel(const f16* __restrict__ h2f,
                          const float* __restrict__ fcw,
                          const float* __restrict__ fcb,
                          float* __restrict__ out) {
    __shared__ float red[256];
    const int tid = threadIdx.x;
    const int b = tid >> 2, q = tid & 3;
    float s = 0.f;
    for (int oct = q * 32; oct < (q + 1) * 32; ++oct) {
        f16x8 v = *(const f16x8*)(h2f + oct * 512 + b * 8);
        #pragma unroll
        for (int j = 0; j < 8; ++j)
            s = fmaf((float)v[j], fcw[oct * 8 + j], s);
    }
    red[tid] = s;
    __syncthreads();
    if (q == 0)
        out[b] = red[tid] + red[tid + 1] + red[tid + 2] + red[tid + 3] + fcb[0];
}

// ---------------------------------------------------------------------------
extern "C" void kernel_launch(void* const* d_in, const int* in_sizes, int n_in,
                              void* d_out, int out_size, void* d_ws, size_t ws_size,
                              hipStream_t stream) {
    const float* x    = (const float*)d_in[0];
    const float* Wih0 = (const float*)d_in[1];
    const float* Whh0 = (const float*)d_in[2];
    const float* bih0 = (const float*)d_in[3];
    const float* bhh0 = (const float*)d_in[4];
    const float* Wih1 = (const float*)d_in[5];
    const float* Whh1 = (const float*)d_in[6];
    const float* bih1 = (const float*)d_in[7];
    const float* bhh1 = (const float*)d_in[8];
    const float* fcw  = (const float*)d_in[9];
    const float* fcb  = (const float*)d_in[10];
    float* out = (float*)d_out;

    // workspace (halfs): xP | Wc0 | Wh0 | Wc1 | Wh1 | ring1 | ring2 | barriers
    f16* xPd   = (f16*)d_ws;
    f16* Wc0   = xPd + (size_t)TDIM * BDIM * KIN;
    f16* Wh0   = Wc0 + (size_t)4 * HDIM * KIN;
    f16* Wc1   = Wh0 + (size_t)4 * HDIM * HDIM;
    f16* Wh1   = Wc1 + (size_t)4 * HDIM * HDIM;
    f16* ring1 = Wh1 + (size_t)4 * HDIM * HDIM;
    f16* ring2 = ring1 + 2 * FRAME;
    unsigned* barA = (unsigned*)(ring2 + 2 * FRAME);
    unsigned* barB = barA + 1024;

    hipMemsetAsync(barA, 0, 8192, stream);
    {
        int n2 = 4 * HDIM * KIN / 2;
        cvt_w<<<dim3((n2 + 255) / 256), dim3(256), 0, stream>>>(Wih0, Wc0, n2);
        n2 = 4 * HDIM * HDIM / 2;
        cvt_w<<<dim3((n2 + 255) / 256), dim3(256), 0, stream>>>(Whh0, Wh0, n2);
        cvt_w<<<dim3((n2 + 255) / 256), dim3(256), 0, stream>>>(Whh1, Wh1, n2);
        cvt_w<<<dim3((n2 + 255) / 256), dim3(256), 0, stream>>>(Wih1, Wc1, n2);
    }
    {
        int np = TDIM * BDIM * (KIN / 2);
        cvt_x<<<dim3((np + 255) / 256), dim3(256), 0, stream>>>(x, xPd);
    }

    void* args[13];
    args[0]  = (void*)&xPd;
    args[1]  = (void*)&Wc0;
    args[2]  = (void*)&Wh0;
    args[3]  = (void*)&bih0;
    args[4]  = (void*)&bhh0;
    args[5]  = (void*)&Wc1;
    args[6]  = (void*)&Wh1;
    args[7]  = (void*)&bih1;
    args[8]  = (void*)&bhh1;
    args[9]  = (void*)&ring1;
    args[10] = (void*)&ring2;
    args[11] = (void*)&barA;
    args[12] = (void*)&barB;
    hipLaunchCooperativeKernel(reinterpret_cast<void*>(lstm_fused), dim3(NBLK), dim3(NTHR),
                               args, 0, stream);

    fc_kernel<<<dim3(1), dim3(256), 0, stream>>>(ring2 + FRAME, fcw, fcb, out);
}